// Round 1
// baseline (206.108 us; speedup 1.0000x reference)
//
#include <hip/hip_runtime.h>

#define B_   8
#define L_   4096
#define DI_  512
#define NCH  64      // scan chunks
#define CL   64      // chunk length (NCH*CL == L_)

// ---- workspace layout (float offsets) ----
#define OFF_CWW  0u          // [512][16]  conv_w[d][j] * W[d][c]
#define OFF_CWB  8192u       // [512][4]   conv_w[d][j] * bias[d]
#define OFF_A2   10240u      // [512][16]  -exp(A_log)
#define OFF_WZ   18432u      // [512][4]   folded z-projection
#define OFF_BZ   20480u      // [512]
#define OFF_XPT  20992u      // [512][48]  xp_w transposed
#define OFF_XDBL 45568u      // [32768][48]
#define OFF_P    1618432u    // [8][64][512][16]
#define OFF_S    5812736u    // [8][64][512][16]
#define OFF_YG   10007040u   // [8][512]
// total = 10011136 floats = 40.0 MB

__device__ __forceinline__ float silu_f(float v) {
  return v * __fdividef(1.f, 1.f + __expf(-v));
}

// ---------------------------------------------------------------- K0: fold weights
__global__ __launch_bounds__(256) void k0_pre(
    const float* __restrict__ ip_w, const float* __restrict__ ip_b,
    const float* __restrict__ in_w, const float* __restrict__ conv_w,
    const float* __restrict__ xp_w, const float* __restrict__ A_log,
    float* __restrict__ ws) {
  const int tid = blockIdx.x * 256 + threadIdx.x;   // grid 64 -> 16384 threads
  const int rowid = tid >> 4;                       // 0..1023 (in_w row)
  const int sub = tid & 15;

  const float* row = in_w + (size_t)rowid * 256;
  float W0 = 0.f, W1 = 0.f, W2 = 0.f, W3 = 0.f, bias = 0.f;
  for (int i = 0; i < 16; ++i) {
    int k = i * 16 + sub;
    float w = row[k];
    float4 ip = ((const float4*)ip_w)[k];
    W0 = fmaf(w, ip.x, W0);
    W1 = fmaf(w, ip.y, W1);
    W2 = fmaf(w, ip.z, W2);
    W3 = fmaf(w, ip.w, W3);
    bias = fmaf(w, ip_b[k], bias);
  }
  for (int off = 8; off; off >>= 1) {
    W0 += __shfl_xor(W0, off, 16);
    W1 += __shfl_xor(W1, off, 16);
    W2 += __shfl_xor(W2, off, 16);
    W3 += __shfl_xor(W3, off, 16);
    bias += __shfl_xor(bias, off, 16);
  }
  if (sub == 0) {
    int d = rowid & 511;
    if (rowid < 512) {
      for (int j = 0; j < 4; ++j) {
        float cw = conv_w[d * 4 + j];
        ws[OFF_CWW + d * 16 + j * 4 + 0] = cw * W0;
        ws[OFF_CWW + d * 16 + j * 4 + 1] = cw * W1;
        ws[OFF_CWW + d * 16 + j * 4 + 2] = cw * W2;
        ws[OFF_CWW + d * 16 + j * 4 + 3] = cw * W3;
        ws[OFF_CWB + d * 4 + j] = cw * bias;
      }
      for (int nn = 0; nn < 16; ++nn)
        ws[OFF_A2 + d * 16 + nn] = -__expf(A_log[d * 16 + nn]);
    } else {
      ws[OFF_WZ + d * 4 + 0] = W0;
      ws[OFF_WZ + d * 4 + 1] = W1;
      ws[OFF_WZ + d * 4 + 2] = W2;
      ws[OFF_WZ + d * 4 + 3] = W3;
      ws[OFF_BZ + d] = bias;
    }
  }
  // transpose xp_w (48,512) -> xpT (512,48)
  for (int i = tid; i < 512 * 48; i += 64 * 256) {
    int d = i / 48, n = i - d * 48;
    ws[OFF_XPT + i] = xp_w[n * 512 + d];
  }
}

// ---------------------------------------------------------------- K2: x_dbl = silu(conv(x@W))@xp_w.T
// 512 blocks x 256.  Each block: 64 rows (t), 4 waves split K=512 into 128-d ranges.
__global__ __launch_bounds__(256) void k2_xdbl(
    const float* __restrict__ x, const float* __restrict__ conv_b,
    const float* __restrict__ cww, const float* __restrict__ cwb,
    const float* __restrict__ xpt, float* __restrict__ xdbl) {
  __shared__ float red[256][49];
  const int tid = threadIdx.x;
  const int q = __builtin_amdgcn_readfirstlane(tid >> 6);  // wave-uniform d-group
  const int rl = tid & 63;
  const int m = blockIdx.x * 64 + rl;
  const int b = m >> 12, t = m & 4095;
  const float4* x4 = (const float4*)x;
  float4 xw[4];
  float msk[4];
#pragma unroll
  for (int j = 0; j < 4; ++j) {
    int s = t - 3 + j;
    xw[j] = (s >= 0) ? x4[b * L_ + s] : make_float4(0.f, 0.f, 0.f, 0.f);
    msk[j] = (s >= 0) ? 1.f : 0.f;
  }
  float acc[48];
#pragma unroll
  for (int n = 0; n < 48; ++n) acc[n] = 0.f;
  const int d0 = q * 128;
  for (int d = d0; d < d0 + 128; ++d) {
    const float* cr = cww + d * 16;
    const float* cb4 = cwb + d * 4;
    float pre = conv_b[d];
#pragma unroll
    for (int j = 0; j < 4; ++j) {
      pre = fmaf(xw[j].x, cr[j * 4 + 0], pre);
      pre = fmaf(xw[j].y, cr[j * 4 + 1], pre);
      pre = fmaf(xw[j].z, cr[j * 4 + 2], pre);
      pre = fmaf(xw[j].w, cr[j * 4 + 3], pre);
      pre = fmaf(msk[j], cb4[j], pre);
    }
    float xc = silu_f(pre);
    const float* xr = xpt + d * 48;
#pragma unroll
    for (int n = 0; n < 48; ++n) acc[n] = fmaf(xc, xr[n], acc[n]);
  }
#pragma unroll
  for (int n = 0; n < 48; ++n) red[tid][n] = acc[n];
  __syncthreads();
  {
    const int r = tid & 63;
    const int ng = tid >> 6;
    float* orow = xdbl + (size_t)(blockIdx.x * 64 + r) * 48;
#pragma unroll
    for (int jj = 0; jj < 12; ++jj) {
      int n = ng * 12 + jj;
      orow[n] = (red[r][n] + red[64 + r][n]) + (red[128 + r][n] + red[192 + r][n]);
    }
  }
}

// ---------------------------------------------------------------- K3: chunked selective scan
// 1024 blocks x 256: block = (b, chunk, d-half). Thread owns one d, 16-n state.
// Emits P = exp(A * sum dt) and S with h_out = P*h_in + S for its chunk.
__global__ __launch_bounds__(256) void k3_scan(
    const float* __restrict__ x, const float* __restrict__ conv_b,
    const float* __restrict__ dt_w, const float* __restrict__ dt_b,
    const float* __restrict__ cww, const float* __restrict__ cwb,
    const float* __restrict__ a2t, const float* __restrict__ xdbl,
    float* __restrict__ Pb, float* __restrict__ Sb) {
  const int blk = blockIdx.x;
  const int b = blk >> 7;
  const int ch = (blk >> 1) & 63;
  const int dg = blk & 1;
  const int d = dg * 256 + threadIdx.x;

  float a2[16], dtw[16], cwwv[16], cwbv[4];
#pragma unroll
  for (int i = 0; i < 16; ++i) a2[i] = a2t[d * 16 + i];
#pragma unroll
  for (int i = 0; i < 16; ++i) dtw[i] = dt_w[d * 16 + i];
#pragma unroll
  for (int i = 0; i < 16; ++i) cwwv[i] = cww[d * 16 + i];
#pragma unroll
  for (int j = 0; j < 4; ++j) cwbv[j] = cwb[d * 4 + j];
  const float dtb = dt_b[d], cb = conv_b[d];
  const float cwbsum = (cwbv[0] + cwbv[1]) + (cwbv[2] + cwbv[3]);

  float S[16];
#pragma unroll
  for (int n = 0; n < 16; ++n) S[n] = 0.f;
  float dtsum = 0.f;

  const int t0 = ch * CL;
  const float4* x4 = (const float4*)x;
  const float4 fz = make_float4(0.f, 0.f, 0.f, 0.f);
  float4 xw0 = (t0 >= 3) ? x4[b * L_ + t0 - 3] : fz;
  float4 xw1 = (t0 >= 2) ? x4[b * L_ + t0 - 2] : fz;
  float4 xw2 = (t0 >= 1) ? x4[b * L_ + t0 - 1] : fz;
  const float* xdb = xdbl + (size_t)b * L_ * 48;

  for (int tt = 0; tt < CL; ++tt) {
    const int t = t0 + tt;
    float4 xw3 = x4[b * L_ + t];
    const float4* row = (const float4*)(xdb + (size_t)t * 48);
    const float4 q0 = row[0], q1 = row[1], q2 = row[2], q3 = row[3];  // dt_in
    const float4 r0 = row[4], r1 = row[5], r2 = row[6], r3 = row[7];  // B

    float s0 = fmaf(q0.x, dtw[0], fmaf(q0.y, dtw[1], fmaf(q0.z, dtw[2], q0.w * dtw[3])));
    float s1 = fmaf(q1.x, dtw[4], fmaf(q1.y, dtw[5], fmaf(q1.z, dtw[6], q1.w * dtw[7])));
    float s2 = fmaf(q2.x, dtw[8], fmaf(q2.y, dtw[9], fmaf(q2.z, dtw[10], q2.w * dtw[11])));
    float s3 = fmaf(q3.x, dtw[12], fmaf(q3.y, dtw[13], fmaf(q3.z, dtw[14], q3.w * dtw[15])));
    float dtpre = dtb + ((s0 + s1) + (s2 + s3));
    float dtv = (dtpre > 15.f) ? dtpre : __logf(1.f + __expf(dtpre));

    float cwbadd = cwbsum;
    if (t < 3) {
      cwbadd = 0.f;
#pragma unroll
      for (int j = 0; j < 4; ++j)
        if (t - 3 + j >= 0) cwbadd += cwbv[j];
    }
    float p0 = fmaf(xw0.x, cwwv[0], fmaf(xw0.y, cwwv[1], fmaf(xw0.z, cwwv[2], xw0.w * cwwv[3])));
    float p1 = fmaf(xw1.x, cwwv[4], fmaf(xw1.y, cwwv[5], fmaf(xw1.z, cwwv[6], xw1.w * cwwv[7])));
    float p2 = fmaf(xw2.x, cwwv[8], fmaf(xw2.y, cwwv[9], fmaf(xw2.z, cwwv[10], xw2.w * cwwv[11])));
    float p3 = fmaf(xw3.x, cwwv[12], fmaf(xw3.y, cwwv[13], fmaf(xw3.z, cwwv[14], xw3.w * cwwv[15])));
    float pre = cb + cwbadd + ((p0 + p1) + (p2 + p3));
    float xc = silu_f(pre);

    float dx = dtv * xc;
    dtsum += dtv;
    float bv[16] = {r0.x, r0.y, r0.z, r0.w, r1.x, r1.y, r1.z, r1.w,
                    r2.x, r2.y, r2.z, r2.w, r3.x, r3.y, r3.z, r3.w};
#pragma unroll
    for (int n = 0; n < 16; ++n) {
      float a = __expf(dtv * a2[n]);
      S[n] = fmaf(a, S[n], dx * bv[n]);
    }
    xw0 = xw1; xw1 = xw2; xw2 = xw3;
  }

  const size_t base = (((size_t)(b * NCH + ch)) * 512 + d) * 16;
  float4* Pp = (float4*)(Pb + base);
  float4* Sp = (float4*)(Sb + base);
#pragma unroll
  for (int i = 0; i < 4; ++i) {
    Pp[i] = make_float4(__expf(a2[4 * i + 0] * dtsum), __expf(a2[4 * i + 1] * dtsum),
                        __expf(a2[4 * i + 2] * dtsum), __expf(a2[4 * i + 3] * dtsum));
    Sp[i] = make_float4(S[4 * i + 0], S[4 * i + 1], S[4 * i + 2], S[4 * i + 3]);
  }
}

// ---------------------------------------------------------------- K4: combine chunks + y readout + gate
__global__ __launch_bounds__(256) void k4_comb(
    const float* __restrict__ x, const float* __restrict__ conv_b,
    const float* __restrict__ Dv, const float* __restrict__ cww,
    const float* __restrict__ cwb, const float* __restrict__ wz,
    const float* __restrict__ bz, const float* __restrict__ xdbl,
    const float* __restrict__ Pb, const float* __restrict__ Sb,
    float* __restrict__ yg) {
  const int idx = blockIdx.x * 256 + threadIdx.x;  // grid 256 -> 65536
  const int n = idx & 15;
  const int d = (idx >> 4) & 511;
  const int b = idx >> 13;
  float h = 0.f;
  for (int ch = 0; ch < NCH; ++ch) {
    const size_t base = ((size_t)(b * NCH + ch)) * 8192 + (idx & 8191);
    h = fmaf(Pb[base], h, Sb[base]);
  }
  const float c = xdbl[((size_t)(b * L_ + (L_ - 1))) * 48 + 32 + n];
  float hc = h * c;
  hc += __shfl_xor(hc, 8, 16);
  hc += __shfl_xor(hc, 4, 16);
  hc += __shfl_xor(hc, 2, 16);
  hc += __shfl_xor(hc, 1, 16);
  if (n == 0) {
    const float4* x4 = (const float4*)x;
    float4 xa = x4[b * L_ + L_ - 4], xb = x4[b * L_ + L_ - 3];
    float4 xc4 = x4[b * L_ + L_ - 2], xd4 = x4[b * L_ + L_ - 1];
    const float* cr = cww + d * 16;
    const float* cb4 = cwb + d * 4;
    float pre = conv_b[d] + ((cb4[0] + cb4[1]) + (cb4[2] + cb4[3]));
    pre += xa.x * cr[0] + xa.y * cr[1] + xa.z * cr[2] + xa.w * cr[3];
    pre += xb.x * cr[4] + xb.y * cr[5] + xb.z * cr[6] + xb.w * cr[7];
    pre += xc4.x * cr[8] + xc4.y * cr[9] + xc4.z * cr[10] + xc4.w * cr[11];
    pre += xd4.x * cr[12] + xd4.y * cr[13] + xd4.z * cr[14] + xd4.w * cr[15];
    float xcl = silu_f(pre);
    float z = bz[d] + xd4.x * wz[d * 4 + 0] + xd4.y * wz[d * 4 + 1] +
              xd4.z * wz[d * 4 + 2] + xd4.w * wz[d * 4 + 3];
    float zs = silu_f(z);
    yg[b * 512 + d] = (hc + Dv[d] * xcl) * zs;
  }
}

// ---------------------------------------------------------------- K5: out = yg @ out_w.T (last row only)
__global__ __launch_bounds__(256) void k5_out(
    const float* __restrict__ yg, const float* __restrict__ out_w,
    float* __restrict__ out) {
  __shared__ float ys[512];
  const int b = blockIdx.x, tid = threadIdx.x;
  ys[tid] = yg[b * 512 + tid];
  ys[256 + tid] = yg[b * 512 + 256 + tid];
  __syncthreads();
  const float4* wr = (const float4*)(out_w + (size_t)tid * 512);
  float a0 = 0.f, a1 = 0.f, a2 = 0.f, a3 = 0.f;
  for (int k = 0; k < 128; ++k) {
    float4 w = wr[k];
    a0 = fmaf(w.x, ys[4 * k + 0], a0);
    a1 = fmaf(w.y, ys[4 * k + 1], a1);
    a2 = fmaf(w.z, ys[4 * k + 2], a2);
    a3 = fmaf(w.w, ys[4 * k + 3], a3);
  }
  out[b * 256 + tid] = (a0 + a1) + (a2 + a3);
}

extern "C" void kernel_launch(void* const* d_in, const int* in_sizes, int n_in,
                              void* d_out, int out_size, void* d_ws, size_t ws_size,
                              hipStream_t stream) {
  const float* x      = (const float*)d_in[0];
  const float* ip_w   = (const float*)d_in[1];
  const float* ip_b   = (const float*)d_in[2];
  const float* in_w   = (const float*)d_in[3];
  const float* conv_w = (const float*)d_in[4];
  const float* conv_b = (const float*)d_in[5];
  const float* xp_w   = (const float*)d_in[6];
  const float* dt_w   = (const float*)d_in[7];
  const float* dt_b   = (const float*)d_in[8];
  const float* A_log  = (const float*)d_in[9];
  const float* Dv     = (const float*)d_in[10];
  const float* out_w  = (const float*)d_in[11];
  float* ws = (float*)d_ws;
  float* out = (float*)d_out;

  k0_pre<<<dim3(64), dim3(256), 0, stream>>>(ip_w, ip_b, in_w, conv_w, xp_w, A_log, ws);
  k2_xdbl<<<dim3(512), dim3(256), 0, stream>>>(x, conv_b, ws + OFF_CWW, ws + OFF_CWB,
                                               ws + OFF_XPT, ws + OFF_XDBL);
  k3_scan<<<dim3(1024), dim3(256), 0, stream>>>(x, conv_b, dt_w, dt_b, ws + OFF_CWW,
                                                ws + OFF_CWB, ws + OFF_A2, ws + OFF_XDBL,
                                                ws + OFF_P, ws + OFF_S);
  k4_comb<<<dim3(256), dim3(256), 0, stream>>>(x, conv_b, Dv, ws + OFF_CWW, ws + OFF_CWB,
                                               ws + OFF_WZ, ws + OFF_BZ, ws + OFF_XDBL,
                                               ws + OFF_P, ws + OFF_S, ws + OFF_YG);
  k5_out<<<dim3(8), dim3(256), 0, stream>>>(ws + OFF_YG, out_w, out);
}